// Round 12
// baseline (317.567 us; speedup 1.0000x reference)
//
#include <hip/hip_runtime.h>
#include <math.h>

// Problem constants
#define NB 8        // batch
#define NC 256      // channels (DIM)
#define NPIX 4096   // H*W
#define NO3 1536    // 3*HIDDEN
#define NHID 512    // HIDDEN
#define NHEADS 8
#define NDH 64
#define NPART 16    // k_context n-partials

typedef unsigned short u16;
typedef __attribute__((ext_vector_type(8))) short short8;
typedef __attribute__((ext_vector_type(4))) float f32x4;

// Workspace layout (float offsets). qkv stays fp32 (precision guard for softmaxes).
// d_out doubles as scratch before GEMM2 writes it: first half xbfT (bf16 normalized
// input, 16.8MB), second half ctxp16 (16 context partials, 16.8MB). Both dead by GEMM2.
// No-max-softmax note: |q|,|k| <= ||xn||*||w_row|| ~ 16 -> exp() fp32-safe; softmax is
// shift-invariant so results match the reference modulo rounding.
#define WS_KSUM  0          // [NB*NHID]
#define WS_CTX   8192       // [64][64][64] reduced context (262144 floats)
#define WS_WQBF  1056768    // ushort[1536*256]  (as float region: 196608)
#define WS_WOBF  1253376    // ushort[256*512]   (as float region: 65536)
#define WS_QKV   1318912    // [NB][1536][4096] fp32
// total = 1318912 + 50331648 = 51,650,560 floats ~= 206.6 MB (proven budget)

__device__ __forceinline__ u16 f2bf(float f) {
    unsigned u = __builtin_bit_cast(unsigned, f);
    unsigned r = (u + 0x7FFFu + ((u >> 16) & 1u)) >> 16;   // RTN-even
    return (u16)r;
}

typedef const __attribute__((address_space(1))) unsigned int guint;
typedef __attribute__((address_space(3))) unsigned int luint;

// ---------------------------------------------------------------- K1: fused pixel-scale + transpose + bf16 convert
__global__ __launch_bounds__(256) void k_scale_convert(const float* __restrict__ x,
                                                        const float* __restrict__ norm_w,
                                                        u16* __restrict__ xbfT) {
    __shared__ float xs[64][257];
    __shared__ float red[4][64];
    __shared__ float ssh[64];
    int blk = blockIdx.x;
    int b = blk >> 6;
    int n0 = (blk & 63) * 64;
    const float* xb = x + (size_t)b * NC * NPIX;
    int t = threadIdx.x;
    int p = t & 63, q = t >> 6;
    float accv = 0.f;
    #pragma unroll 8
    for (int c = q * 64; c < q * 64 + 64; ++c) {
        float v = xb[(size_t)c * NPIX + n0 + p];
        xs[p][c] = v;
        accv = fmaf(v, v, accv);
    }
    red[q][p] = accv;
    __syncthreads();
    if (t < 64) {
        float sum = red[0][t] + red[1][t] + red[2][t] + red[3][t];
        ssh[t] = 16.0f / fmaxf(sqrtf(sum), 1e-12f);
    }
    __syncthreads();
    int p2 = t >> 2, cbase = (t & 3) * 64;
    float sc = ssh[p2];
    u16* orow = xbfT + (size_t)(b * NPIX + n0 + p2) * NC + cbase;
    #pragma unroll
    for (int j = 0; j < 64; j += 8) {
        union { u16 us[8]; uint4 v; } pk;
        #pragma unroll
        for (int u = 0; u < 8; ++u)
            pk.us[u] = f2bf(xs[p2][cbase + j + u] * norm_w[cbase + j + u] * sc);
        *(uint4*)(orow + j) = pk.v;
    }
}

// ---------------------------------------------------------------- K2: weight bf16 convert (wq and wo)
__global__ __launch_bounds__(256) void k_wconv(const float* __restrict__ wq, const float* __restrict__ wo,
                                                u16* __restrict__ wqbf, u16* __restrict__ wobf) {
    int idx = blockIdx.x * 256 + threadIdx.x;
    int e = idx * 4;
    if (e < 393216) {
        float4 v = *(const float4*)(wq + e);
        union { u16 us[4]; uint2 v2; } pk;
        pk.us[0] = f2bf(v.x); pk.us[1] = f2bf(v.y); pk.us[2] = f2bf(v.z); pk.us[3] = f2bf(v.w);
        *(uint2*)(wqbf + e) = pk.v2;
    } else {
        int e2 = e - 393216;
        float4 v = *(const float4*)(wo + e2);
        union { u16 us[4]; uint2 v2; } pk;
        pk.us[0] = f2bf(v.x); pk.us[1] = f2bf(v.y); pk.us[2] = f2bf(v.z); pk.us[3] = f2bf(v.w);
        *(uint2*)(wobf + e2) = pk.v2;
    }
}

// ---------------------------------------------------------------- MFMA NT-GEMM (m97 structure)
template<int KD, bool BIAS>
__global__ __launch_bounds__(256) void k_mfma_nt(const u16* __restrict__ A, const u16* __restrict__ B,
                                                  const float* __restrict__ bias, float* __restrict__ C,
                                                  size_t bStride, size_t cStride) {
    __shared__ u16 lA[128 * 64];
    __shared__ u16 lB[128 * 64];
    const int b = blockIdx.z;
    const int m0 = blockIdx.y * 128;
    const int n0 = blockIdx.x * 128;
    const u16* Bb = B + (size_t)b * bStride;
    float* Cb = C + (size_t)b * cStride;
    const int t = threadIdx.x;
    const int lane = t & 63;
    const int wid = t >> 6;
    const int wr = (wid >> 1) * 64;
    const int wc = (wid & 1) * 64;
    const int fr = lane & 15;
    const int fq = lane >> 4;

    f32x4 acc[4][4];
    #pragma unroll
    for (int i = 0; i < 4; ++i)
        #pragma unroll
        for (int j = 0; j < 4; ++j) acc[i][j] = (f32x4){0.f, 0.f, 0.f, 0.f};

    for (int k0 = 0; k0 < KD; k0 += 64) {
        #pragma unroll
        for (int i = 0; i < 4; ++i) {
            int idx = i * 256 + t;
            int row = idx >> 3;
            int col = (idx & 7) * 8;
            __builtin_amdgcn_global_load_lds((guint*)(A + (size_t)(m0 + row) * KD + k0 + col),
                                             (luint*)(&lA[idx * 8]), 16, 0, 0);
            __builtin_amdgcn_global_load_lds((guint*)(Bb + (size_t)(n0 + row) * KD + k0 + col),
                                             (luint*)(&lB[idx * 8]), 16, 0, 0);
        }
        __syncthreads();
        #pragma unroll
        for (int kk = 0; kk < 2; ++kk) {
            short8 af[4], bfv[4];
            #pragma unroll
            for (int i = 0; i < 4; ++i)
                af[i] = *(const short8*)&lA[(wr + i * 16 + fr) * 64 + kk * 32 + fq * 8];
            #pragma unroll
            for (int j = 0; j < 4; ++j)
                bfv[j] = *(const short8*)&lB[(wc + j * 16 + fr) * 64 + kk * 32 + fq * 8];
            #pragma unroll
            for (int i = 0; i < 4; ++i)
                #pragma unroll
                for (int j = 0; j < 4; ++j)
                    acc[i][j] = __builtin_amdgcn_mfma_f32_16x16x32_bf16(af[i], bfv[j], acc[i][j], 0, 0, 0);
        }
        __syncthreads();
    }
    #pragma unroll
    for (int i = 0; i < 4; ++i) {
        int rbase = m0 + wr + i * 16 + fq * 4;
        #pragma unroll
        for (int j = 0; j < 4; ++j) {
            int c = n0 + wc + j * 16 + fr;
            #pragma unroll
            for (int r = 0; r < 4; ++r) {
                float v = acc[i][j][r];
                if (BIAS) v += bias[rbase + r];
                Cb[(size_t)(rbase + r) * NPIX + c] = v;
            }
        }
    }
}

// ---------------------------------------------------------------- K4: k-row sum-exp over 4104 (no max: |k|<=16 bounded)
__global__ __launch_bounds__(256) void k_k_stats(const float* __restrict__ qkv, const float* __restrict__ mem_kv,
                                                 float* __restrict__ ksum) {
    int row = blockIdx.x;
    int b = row >> 9, hd = row & 511;
    int h = hd >> 6, d = hd & 63;
    const float* kp = qkv + ((size_t)b * NO3 + NHID + hd) * NPIX;
    int t = threadIdx.x;
    float sum = 0.f;
    const float4* kp4 = (const float4*)kp;
    #pragma unroll
    for (int i = t; i < 1024; i += 256) {
        float4 v = kp4[i];
        sum += __expf(v.x) + __expf(v.y) + __expf(v.z) + __expf(v.w);
    }
    if (t < 8) sum += __expf(mem_kv[((size_t)h * 64 + d) * 8 + t]);
    __shared__ float ss[256];
    ss[t] = sum;
    __syncthreads();
    for (int st = 128; st > 0; st >>= 1) {
        if (t < st) ss[t] += ss[t + st];
        __syncthreads();
    }
    if (t == 0) ksum[row] = ss[0];
}

// ---------------------------------------------------------------- K5: context partials (NPART=16; exp(k)*inv, no max)
__global__ __launch_bounds__(256) void k_context(const float* __restrict__ qkv, const float* __restrict__ mem_kv,
                                                 const float* __restrict__ ksum,
                                                 float* __restrict__ ctxp) {
    int bh = blockIdx.x;
    int p = blockIdx.y;
    int b = bh >> 3, h = bh & 7;
    const float* kp = qkv + ((size_t)b * NO3 + NHID + h * NDH) * NPIX;
    const float* vp = qkv + ((size_t)b * NO3 + 2 * NHID + h * NDH) * NPIX;
    __shared__ float KsT[64][68];
    __shared__ float VsT[64][68];
    __shared__ float sinv[64];
    int t = threadIdx.x;
    if (t < 64) sinv[t] = 1.0f / ksum[bh * 64 + t];
    __syncthreads();
    int tx = t & 15, ty = t >> 4;
    int d0 = ty * 4, e0 = tx * 4;
    float acc[4][4] = {{0.f}};
    if (p == 0) {
        const float* mkp = mem_kv + (size_t)h * 64 * 8;
        const float* mvp = mem_kv + (size_t)NHEADS * 64 * 8 + (size_t)h * 64 * 8;
        #pragma unroll
        for (int j = 0; j < 8; ++j) {
            float vv[4];
            #pragma unroll
            for (int q = 0; q < 4; ++q) vv[q] = mvp[(e0 + q) * 8 + j];
            #pragma unroll
            for (int i = 0; i < 4; ++i) {
                float kk = __expf(mkp[(d0 + i) * 8 + j]) * sinv[d0 + i];
                #pragma unroll
                for (int q = 0; q < 4; ++q) acc[i][q] = fmaf(kk, vv[q], acc[i][q]);
            }
        }
    }
    int rr = t >> 6, cc = t & 63;
    for (int n0 = p * 256; n0 < p * 256 + 256; n0 += 64) {
        #pragma unroll
        for (int i = 0; i < 16; ++i) {
            int row = rr + i * 4;
            float kv = kp[(size_t)row * NPIX + n0 + cc];
            KsT[cc][row] = __expf(kv) * sinv[row];
            VsT[cc][row] = vp[(size_t)row * NPIX + n0 + cc];
        }
        __syncthreads();
        #pragma unroll 4
        for (int n = 0; n < 64; ++n) {
            float4 a = *(const float4*)&KsT[n][d0];
            float4 vv = *(const float4*)&VsT[n][e0];
            float av[4] = {a.x, a.y, a.z, a.w};
            float vvv[4] = {vv.x, vv.y, vv.z, vv.w};
            #pragma unroll
            for (int i = 0; i < 4; ++i)
                #pragma unroll
                for (int q = 0; q < 4; ++q) acc[i][q] = fmaf(av[i], vvv[q], acc[i][q]);
        }
        __syncthreads();
    }
    #pragma unroll
    for (int i = 0; i < 4; ++i)
        #pragma unroll
        for (int q = 0; q < 4; ++q)
            ctxp[(((size_t)p * 64 + bh) * 64 + d0 + i) * 64 + e0 + q] = acc[i][q];
}

// ---------------------------------------------------------------- K5b: reduce 16 context partials -> ctx
__global__ __launch_bounds__(256) void k_ctx_reduce(const float* __restrict__ ctxp, float* __restrict__ ctx) {
    int idx = blockIdx.x * 256 + threadIdx.x;
    float s = 0.f;
    #pragma unroll
    for (int p = 0; p < NPART; ++p) s += ctxp[(size_t)p * 262144 + idx];
    ctx[idx] = s;
}

// ---------------------------------------------------------------- K6: fused q-softmax + PV, single pass (no max):
// out[n][e] = (sum_d exp(q_d)*ctx[d][e]) * 0.125/(sum_d exp(q_d)). Independent exps
// pipeline into 64 static accumulators -> no serial chain, no spill.
__global__ __launch_bounds__(256) void k_pv(float* __restrict__ qkv, const float* __restrict__ ctx) {
    int nb = blockIdx.x;                            // 16 column blocks of 256
    int bh = blockIdx.y;                            // 64
    int b = bh >> 3, h = bh & 7;
    __shared__ float Cs[64][64];
    int t = threadIdx.x;
    for (int i = t; i < 4096; i += 256)
        Cs[i >> 6][i & 63] = ctx[(size_t)bh * 4096 + i];
    __syncthreads();
    int n = nb * 256 + t;
    const float* qp = qkv + ((size_t)b * NO3 + h * NDH) * NPIX + n;
    float sum = 0.f;
    float acc[64];
    #pragma unroll
    for (int e = 0; e < 64; ++e) acc[e] = 0.f;
    for (int d = 0; d < 64; ++d) {
        float w = __expf(qp[(size_t)d * NPIX]);
        sum += w;
        const float4* crow = (const float4*)&Cs[d][0];
        #pragma unroll
        for (int e4 = 0; e4 < 16; ++e4) {
            float4 cv = crow[e4];
            acc[e4 * 4 + 0] = fmaf(cv.x, w, acc[e4 * 4 + 0]);
            acc[e4 * 4 + 1] = fmaf(cv.y, w, acc[e4 * 4 + 1]);
            acc[e4 * 4 + 2] = fmaf(cv.z, w, acc[e4 * 4 + 2]);
            acc[e4 * 4 + 3] = fmaf(cv.w, w, acc[e4 * 4 + 3]);
        }
    }
    float inv = 0.125f / sum;   // * dh^-0.5, softmax denom factored out
    u16* outT = (u16*)(qkv + ((size_t)b * NO3 + NHID) * NPIX);
    u16* op = outT + (size_t)n * NHID + h * NDH;
    #pragma unroll
    for (int e8 = 0; e8 < 8; ++e8) {
        union { u16 us[8]; uint4 v; } pk;
        #pragma unroll
        for (int u = 0; u < 8; ++u) pk.us[u] = f2bf(acc[e8 * 8 + u] * inv);
        *(uint4*)(op + e8 * 8) = pk.v;
    }
}

// ---------------------------------------------------------------- K8: final RMS norm, in place on d_out
__global__ __launch_bounds__(256) void k_out_norm(float* __restrict__ out, const float* __restrict__ onw) {
    int idx = blockIdx.x * 256 + threadIdx.x;
    int b = idx >> 12, n = idx & 4095;
    float* op = out + (size_t)b * NC * NPIX + n;
    float acc = 0.f;
    #pragma unroll 8
    for (int c = 0; c < NC; ++c) { float v = op[(size_t)c * NPIX]; acc = fmaf(v, v, acc); }
    float sc = 16.0f / fmaxf(sqrtf(acc), 1e-12f);
    #pragma unroll 8
    for (int c = 0; c < NC; ++c) op[(size_t)c * NPIX] = op[(size_t)c * NPIX] * (sc * onw[c]);
}

extern "C" void kernel_launch(void* const* d_in, const int* in_sizes, int n_in,
                              void* d_out, int out_size, void* d_ws, size_t ws_size,
                              hipStream_t stream) {
    const float* x      = (const float*)d_in[0];
    const float* norm_w = (const float*)d_in[1];
    const float* w_qkv  = (const float*)d_in[2];
    const float* mem_kv = (const float*)d_in[3];
    const float* w_out  = (const float*)d_in[4];
    const float* b_out  = (const float*)d_in[5];
    const float* onw    = (const float*)d_in[6];
    float* out = (float*)d_out;
    float* ws  = (float*)d_ws;

    float* ksum = ws + WS_KSUM;
    float* ctx  = ws + WS_CTX;
    u16*   wqbf = (u16*)(ws + WS_WQBF);
    u16*   wobf = (u16*)(ws + WS_WOBF);
    float* qkv  = ws + WS_QKV;
    u16*   xbfT  = (u16*)d_out;                       // d_out 1st half: dead until GEMM2
    float* ctxp  = (float*)d_out + 4194304;           // d_out 2nd half: dead until GEMM2
    const u16* outT = (const u16*)(qkv + (size_t)NHID * NPIX);   // per-batch stride NO3*NPIX floats

    k_wconv        <<<dim3(512),            dim3(256), 0, stream>>>(w_qkv, w_out, wqbf, wobf);
    k_scale_convert<<<dim3(NB * 64),        dim3(256), 0, stream>>>(x, norm_w, xbfT);
    k_mfma_nt<256, false><<<dim3(32, 12, NB), dim3(256), 0, stream>>>(
        wqbf, xbfT, nullptr, qkv, (size_t)NPIX * NC, (size_t)NO3 * NPIX);
    k_k_stats      <<<dim3(NB * NHID),      dim3(256), 0, stream>>>(qkv, mem_kv, ksum);
    k_context      <<<dim3(NB * NHEADS, NPART), dim3(256), 0, stream>>>(qkv, mem_kv, ksum, ctxp);
    k_ctx_reduce   <<<dim3(1024),           dim3(256), 0, stream>>>(ctxp, ctx);
    k_pv           <<<dim3(16, NB * NHEADS), dim3(256), 0, stream>>>(qkv, ctx);
    k_mfma_nt<512, true><<<dim3(32, 2, NB), dim3(256), 0, stream>>>(
        wobf, outT, b_out, out, (size_t)NO3 * NPIX * 2, (size_t)NC * NPIX);
    k_out_norm     <<<dim3(NB * NPIX / 256), dim3(256), 0, stream>>>(out, onw);
}